// Round 2
// baseline (444.239 us; speedup 1.0000x reference)
//
#include <hip/hip_runtime.h>
#include <math.h>

#define BN 64
#define PN 8732
#define CN 81
#define GN 32

// ws layout (bytes):
//   0   : float acc[3]  {sl1_sum, ce_pos_sum, hardneg_sum}
//   64  : int n_pos[BN]
//   512 : int idx_per_gt[BN*GN]
//   8704: int cls[BN*PN]
//   2244096: float ce_neg[BN*PN]
#define ACC_OFF   0
#define NPOS_OFF  64
#define IDXG_OFF  512
#define CLS_OFF   8704
#define CEN_OFF   2244096

// ---------------- Pass A: idx_per_gt[b,g] = argmax_p IoU(gt, prior) (first occurrence)
__global__ __launch_bounds__(256) void pass_a(const float* __restrict__ boxes,
                                              const float* __restrict__ prior,
                                              int* __restrict__ idx_per_gt) {
    int b = blockIdx.x / GN, g = blockIdx.x % GN;
    const float4 gbv = *(const float4*)(boxes + (size_t)(b * GN + g) * 4);
    float gx0 = gbv.x, gy0 = gbv.y, gx1 = gbv.z, gy1 = gbv.w;
    float ga = (gx1 - gx0) * (gy1 - gy0);
    const float4* pr4 = (const float4*)prior;
    float best = -1.0f; int bi = PN;
    for (int p = threadIdx.x; p < PN; p += 256) {
        float4 pc = pr4[p];
        float cx = pc.x, cy = pc.y, w = pc.z, h = pc.w;
        float px0 = cx - w * 0.5f, py0 = cy - h * 0.5f;
        float px1 = cx + w * 0.5f, py1 = cy + h * 0.5f;
        float pa = (px1 - px0) * (py1 - py0);
        float ix = fminf(gx1, px1) - fmaxf(gx0, px0); ix = fmaxf(ix, 0.0f);
        float iy = fminf(gy1, py1) - fmaxf(gy0, py0); iy = fmaxf(iy, 0.0f);
        float inter = ix * iy;
        float iou = inter / (ga + pa - inter);
        if (iou > best) { best = iou; bi = p; }   // strict > keeps first occurrence
    }
    // wave butterfly: bigger val wins, tie -> smaller idx
    for (int o = 1; o < 64; o <<= 1) {
        float ov = __shfl_xor(best, o);
        int   oi = __shfl_xor(bi, o);
        if (ov > best || (ov == best && oi < bi)) { best = ov; bi = oi; }
    }
    __shared__ float sv[4]; __shared__ int si[4];
    int wid = threadIdx.x >> 6;
    if ((threadIdx.x & 63) == 0) { sv[wid] = best; si[wid] = bi; }
    __syncthreads();
    if (threadIdx.x == 0) {
        for (int w = 1; w < 4; w++)
            if (sv[w] > best || (sv[w] == best && si[w] < bi)) { best = sv[w]; bi = si[w]; }
        idx_per_gt[b * GN + g] = bi;
    }
}

// ---------------- Pass B: per-prior match, labels, smooth-L1 on positives
__global__ __launch_bounds__(256) void pass_b(const float* __restrict__ pred_boxes,
                                              const float* __restrict__ boxes,
                                              const int* __restrict__ labels,
                                              const float* __restrict__ prior,
                                              const int* __restrict__ idx_per_gt,
                                              int* __restrict__ cls,
                                              float* __restrict__ acc,
                                              int* __restrict__ n_pos) {
    int b = blockIdx.y;
    __shared__ float bx[GN][4];
    __shared__ int lb[GN];
    __shared__ int ig[GN];
    int t = threadIdx.x;
    if (t < GN) {
        const float4 src = *(const float4*)(boxes + (size_t)(b * GN + t) * 4);
        bx[t][0] = src.x; bx[t][1] = src.y; bx[t][2] = src.z; bx[t][3] = src.w;
        lb[t] = labels[b * GN + t];
        ig[t] = idx_per_gt[b * GN + t];
    }
    __syncthreads();
    int p = blockIdx.x * 256 + t;
    float sl1 = 0.0f; int posc = 0;
    if (p < PN) {
        float4 pc = ((const float4*)prior)[p];
        float cx = pc.x, cy = pc.y, w = pc.z, h = pc.w;
        float px0 = cx - w * 0.5f, py0 = cy - h * 0.5f;
        float px1 = cx + w * 0.5f, py1 = cy + h * 0.5f;
        float pa = (px1 - px0) * (py1 - py0);
        float best = -1.0f; int bi = 0;
        for (int g = 0; g < GN; g++) {
            float gx0 = bx[g][0], gy0 = bx[g][1], gx1 = bx[g][2], gy1 = bx[g][3];
            float ga = (gx1 - gx0) * (gy1 - gy0);
            float ix = fminf(gx1, px1) - fmaxf(gx0, px0); ix = fmaxf(ix, 0.0f);
            float iy = fminf(gy1, py1) - fmaxf(gy0, py0); iy = fmaxf(iy, 0.0f);
            float inter = ix * iy;
            float iou = inter / (ga + pa - inter);
            if (iou > best) { best = iou; bi = g; }   // first occurrence along G
        }
        // scatter override: numpy last-g-wins
        for (int g = 0; g < GN; g++) if (ig[g] == p) { bi = g; best = 1.0f; }
        int lab = (best < 0.5f) ? 0 : lb[bi];
        cls[(size_t)b * PN + p] = lab;
        if (lab != 0) {
            posc = 1;
            float gx0 = bx[bi][0], gy0 = bx[bi][1], gx1 = bx[bi][2], gy1 = bx[bi][3];
            float gcx = (gx0 + gx1) * 0.5f, gcy = (gy0 + gy1) * 0.5f;
            float gw = gx1 - gx0, gh = gy1 - gy0;
            float tb0 = (gcx - cx) / (w / 10.0f);
            float tb1 = (gcy - cy) / (h / 10.0f);
            float tb2 = logf(gw / w) * 5.0f;
            float tb3 = logf(gh / h) * 5.0f;
            const float* pb = pred_boxes + (size_t)(b * PN + p) * 4;
            float tb[4] = {tb0, tb1, tb2, tb3};
            for (int i = 0; i < 4; i++) {
                float d = pb[i] - tb[i];
                float ad = fabsf(d);
                sl1 += (ad < 1.0f) ? 0.5f * d * d : (ad - 0.5f);
            }
        }
    }
    for (int o = 1; o < 64; o <<= 1) {
        sl1  += __shfl_xor(sl1, o);
        posc += __shfl_xor(posc, o);
    }
    if ((t & 63) == 0) {
        if (sl1 != 0.0f) atomicAdd(&acc[0], sl1);
        if (posc)        atomicAdd(&n_pos[b], posc);
    }
}

// ---------------- Pass C: cross entropy per (b,p) — register-only, 16 lanes/row
__global__ __launch_bounds__(256) void pass_c(const float* __restrict__ logits,
                                              const int* __restrict__ cls,
                                              float* __restrict__ ce_neg,
                                              float* __restrict__ acc) {
    int tid = threadIdx.x;
    int lane = tid & 63;
    int j = tid & 15;                      // lane within 16-group
    int row = blockIdx.x * 16 + (tid >> 4);
    const float* rp = logits + (size_t)row * CN;
    float v[6];
    #pragma unroll
    for (int u = 0; u < 6; u++) {
        int idx = j + 16 * u;
        v[u] = (idx < CN) ? rp[idx] : -INFINITY;
    }
    float m = v[0];
    #pragma unroll
    for (int u = 1; u < 6; u++) m = fmaxf(m, v[u]);
    #pragma unroll
    for (int o = 1; o < 16; o <<= 1) m = fmaxf(m, __shfl_xor(m, o));
    float se = 0.0f;
    #pragma unroll
    for (int u = 0; u < 6; u++) se += __expf(v[u] - m);   // exp(-inf) = 0
    #pragma unroll
    for (int o = 1; o < 16; o <<= 1) se += __shfl_xor(se, o);
    float logZ = m + __logf(se);
    int lab = cls[row];                    // same for all 16 lanes of the group
    int slot = lab >> 4;
    float vs = v[0];
    vs = (slot == 1) ? v[1] : vs;
    vs = (slot == 2) ? v[2] : vs;
    vs = (slot == 3) ? v[3] : vs;
    vs = (slot == 4) ? v[4] : vs;
    vs = (slot == 5) ? v[5] : vs;
    float xlab = __shfl(vs, (lane & ~15) | (lab & 15), 64);
    float ce = logZ - xlab;
    float cepos = 0.0f;
    if (j == 0) {
        ce_neg[row] = (lab != 0) ? 0.0f : fmaxf(ce, 0.0f);  // clamp keeps bits monotonic
        cepos = (lab != 0) ? ce : 0.0f;
    }
    #pragma unroll
    for (int o = 1; o < 64; o <<= 1) cepos += __shfl_xor(cepos, o);
    if (lane == 0 && cepos != 0.0f) atomicAdd(&acc[1], cepos);
}

// ---------------- Pass D: per-image top-k(3*n_pos) sum of ce_neg, register-resident bisection
__global__ __launch_bounds__(1024) void pass_d(const float* __restrict__ ce_neg,
                                               const int* __restrict__ n_pos,
                                               float* __restrict__ acc) {
    __shared__ int cnt[32];
    __shared__ float ssum;
    __shared__ int scnt;
    int b = blockIdx.x;
    int tid = threadIdx.x;
    int lane = tid & 63;
    float v[9];
    #pragma unroll
    for (int r = 0; r < 9; r++) {
        int i = r * 1024 + tid;
        v[r] = (i < PN) ? ce_neg[(size_t)b * PN + i] : 0.0f;   // pad with 0 (neutral)
    }
    if (tid < 32) cnt[tid] = 0;
    if (tid == 0) { ssum = 0.0f; scnt = 0; }
    __syncthreads();
    int k = 3 * n_pos[b];
    if (k > PN) k = PN;
    if (k == 0) return;   // uniform across block
    unsigned lo = 0u, hi = 0x7f7fffffu;
    int iter = 0;
    if (k < PN) {
        while (lo < hi) {
            unsigned mid = lo + (hi - lo + 1u) / 2u;
            float mf = __uint_as_float(mid);
            int c = 0;
            #pragma unroll
            for (int r = 0; r < 9; r++) c += (v[r] >= mf) ? 1 : 0;
            #pragma unroll
            for (int o = 1; o < 64; o <<= 1) c += __shfl_xor(c, o);
            if (lane == 0) atomicAdd(&cnt[iter], c);
            __syncthreads();
            int tot = cnt[iter];
            if (tot >= k) lo = mid; else hi = mid - 1u;
            iter++;
        }
    }
    float vk = (k < PN) ? __uint_as_float(lo) : -1.0f;
    float s = 0.0f; int cg = 0;
    #pragma unroll
    for (int r = 0; r < 9; r++) {
        if (v[r] > vk) { s += v[r]; cg++; }
    }
    #pragma unroll
    for (int o = 1; o < 64; o <<= 1) { s += __shfl_xor(s, o); cg += __shfl_xor(cg, o); }
    if (lane == 0) { atomicAdd(&ssum, s); atomicAdd(&scnt, cg); }
    __syncthreads();
    if (tid == 0) {
        float res = (k < PN) ? (ssum + vk * (float)(k - scnt)) : ssum;
        atomicAdd(&acc[2], res);
    }
}

// ---------------- Pass E: finalize
__global__ void pass_e(const int* __restrict__ n_pos, const float* __restrict__ acc,
                       float* __restrict__ out) {
    if (threadIdx.x == 0) {
        int npt = 0;
        for (int b = 0; b < BN; b++) npt += n_pos[b];
        float n = (float)npt;
        out[0] = (acc[1] + acc[2]) / n + acc[0] / (n * 4.0f);
    }
}

extern "C" void kernel_launch(void* const* d_in, const int* in_sizes, int n_in,
                              void* d_out, int out_size, void* d_ws, size_t ws_size,
                              hipStream_t stream) {
    const float* pred_boxes  = (const float*)d_in[0];
    const float* pred_logits = (const float*)d_in[1];
    const float* boxes       = (const float*)d_in[2];
    const int*   labels      = (const int*)d_in[3];
    const float* prior       = (const float*)d_in[4];
    float* out = (float*)d_out;
    char* ws = (char*)d_ws;

    float* acc    = (float*)(ws + ACC_OFF);
    int*   n_pos  = (int*)(ws + NPOS_OFF);
    int*   idxg   = (int*)(ws + IDXG_OFF);
    int*   cls    = (int*)(ws + CLS_OFF);
    float* ce_neg = (float*)(ws + CEN_OFF);

    hipMemsetAsync(ws, 0, 512, stream);

    pass_a<<<BN * GN, 256, 0, stream>>>(boxes, prior, idxg);

    dim3 gb((PN + 255) / 256, BN);
    pass_b<<<gb, 256, 0, stream>>>(pred_boxes, boxes, labels, prior, idxg, cls, acc, n_pos);

    pass_c<<<(BN * PN) / 16, 256, 0, stream>>>(pred_logits, cls, ce_neg, acc);

    pass_d<<<BN, 1024, 0, stream>>>(ce_neg, n_pos, acc);

    pass_e<<<1, 64, 0, stream>>>(n_pos, acc, out);
}

// Round 3
// 390.231 us; speedup vs baseline: 1.1384x; 1.1384x over previous
//
#include <hip/hip_runtime.h>
#include <math.h>

#define BN 64
#define PN 8732
#define CN 81
#define GN 32

// ws layout (bytes):
//   0   : float acc[3]  {sl1_sum, ce_pos_sum, hardneg_sum}
//   64  : int n_pos[BN]
//   512 : int idx_per_gt[BN*GN]
//   8704: int cls[BN*PN]
//   2244096: float ce_neg[BN*PN]
#define ACC_OFF   0
#define NPOS_OFF  64
#define IDXG_OFF  512
#define CLS_OFF   8704
#define CEN_OFF   2244096

// ---------------- Pass A: idx_per_gt[b,g] = argmax_p IoU(gt, prior) (first occurrence)
__global__ __launch_bounds__(256) void pass_a(const float* __restrict__ boxes,
                                              const float* __restrict__ prior,
                                              int* __restrict__ idx_per_gt) {
    int b = blockIdx.x / GN, g = blockIdx.x % GN;
    const float4 gbv = *(const float4*)(boxes + (size_t)(b * GN + g) * 4);
    float gx0 = gbv.x, gy0 = gbv.y, gx1 = gbv.z, gy1 = gbv.w;
    float ga = (gx1 - gx0) * (gy1 - gy0);
    const float4* pr4 = (const float4*)prior;
    float best = -1.0f; int bi = PN;
    for (int p = threadIdx.x; p < PN; p += 256) {
        float4 pc = pr4[p];
        float cx = pc.x, cy = pc.y, w = pc.z, h = pc.w;
        float px0 = cx - w * 0.5f, py0 = cy - h * 0.5f;
        float px1 = cx + w * 0.5f, py1 = cy + h * 0.5f;
        float pa = (px1 - px0) * (py1 - py0);
        float ix = fminf(gx1, px1) - fmaxf(gx0, px0); ix = fmaxf(ix, 0.0f);
        float iy = fminf(gy1, py1) - fmaxf(gy0, py0); iy = fmaxf(iy, 0.0f);
        float inter = ix * iy;
        float iou = inter / (ga + pa - inter);
        if (iou > best) { best = iou; bi = p; }   // strict > keeps first occurrence
    }
    // wave butterfly: bigger val wins, tie -> smaller idx
    for (int o = 1; o < 64; o <<= 1) {
        float ov = __shfl_xor(best, o);
        int   oi = __shfl_xor(bi, o);
        if (ov > best || (ov == best && oi < bi)) { best = ov; bi = oi; }
    }
    __shared__ float sv[4]; __shared__ int si[4];
    int wid = threadIdx.x >> 6;
    if ((threadIdx.x & 63) == 0) { sv[wid] = best; si[wid] = bi; }
    __syncthreads();
    if (threadIdx.x == 0) {
        for (int w = 1; w < 4; w++)
            if (sv[w] > best || (sv[w] == best && si[w] < bi)) { best = sv[w]; bi = si[w]; }
        idx_per_gt[b * GN + g] = bi;
    }
}

// ---------------- Pass B: per-prior match, labels, smooth-L1 on positives
__global__ __launch_bounds__(256) void pass_b(const float* __restrict__ pred_boxes,
                                              const float* __restrict__ boxes,
                                              const int* __restrict__ labels,
                                              const float* __restrict__ prior,
                                              const int* __restrict__ idx_per_gt,
                                              int* __restrict__ cls,
                                              float* __restrict__ acc,
                                              int* __restrict__ n_pos) {
    int b = blockIdx.y;
    __shared__ float bx[GN][4];
    __shared__ int lb[GN];
    __shared__ int ig[GN];
    int t = threadIdx.x;
    if (t < GN) {
        const float4 src = *(const float4*)(boxes + (size_t)(b * GN + t) * 4);
        bx[t][0] = src.x; bx[t][1] = src.y; bx[t][2] = src.z; bx[t][3] = src.w;
        lb[t] = labels[b * GN + t];
        ig[t] = idx_per_gt[b * GN + t];
    }
    __syncthreads();
    int p = blockIdx.x * 256 + t;
    float sl1 = 0.0f; int posc = 0;
    if (p < PN) {
        float4 pc = ((const float4*)prior)[p];
        float cx = pc.x, cy = pc.y, w = pc.z, h = pc.w;
        float px0 = cx - w * 0.5f, py0 = cy - h * 0.5f;
        float px1 = cx + w * 0.5f, py1 = cy + h * 0.5f;
        float pa = (px1 - px0) * (py1 - py0);
        float best = -1.0f; int bi = 0;
        for (int g = 0; g < GN; g++) {
            float gx0 = bx[g][0], gy0 = bx[g][1], gx1 = bx[g][2], gy1 = bx[g][3];
            float ga = (gx1 - gx0) * (gy1 - gy0);
            float ix = fminf(gx1, px1) - fmaxf(gx0, px0); ix = fmaxf(ix, 0.0f);
            float iy = fminf(gy1, py1) - fmaxf(gy0, py0); iy = fmaxf(iy, 0.0f);
            float inter = ix * iy;
            float iou = inter / (ga + pa - inter);
            if (iou > best) { best = iou; bi = g; }   // first occurrence along G
        }
        // scatter override: numpy last-g-wins
        for (int g = 0; g < GN; g++) if (ig[g] == p) { bi = g; best = 1.0f; }
        int lab = (best < 0.5f) ? 0 : lb[bi];
        cls[(size_t)b * PN + p] = lab;
        if (lab != 0) {
            posc = 1;
            float gx0 = bx[bi][0], gy0 = bx[bi][1], gx1 = bx[bi][2], gy1 = bx[bi][3];
            float gcx = (gx0 + gx1) * 0.5f, gcy = (gy0 + gy1) * 0.5f;
            float gw = gx1 - gx0, gh = gy1 - gy0;
            float tb0 = (gcx - cx) / (w / 10.0f);
            float tb1 = (gcy - cy) / (h / 10.0f);
            float tb2 = __logf(gw / w) * 5.0f;
            float tb3 = __logf(gh / h) * 5.0f;
            const float* pb = pred_boxes + (size_t)(b * PN + p) * 4;
            float tb[4] = {tb0, tb1, tb2, tb3};
            for (int i = 0; i < 4; i++) {
                float d = pb[i] - tb[i];
                float ad = fabsf(d);
                sl1 += (ad < 1.0f) ? 0.5f * d * d : (ad - 0.5f);
            }
        }
    }
    for (int o = 1; o < 64; o <<= 1) {
        sl1  += __shfl_xor(sl1, o);
        posc += __shfl_xor(posc, o);
    }
    if ((t & 63) == 0) {
        if (sl1 != 0.0f) atomicAdd(&acc[0], sl1);
        if (posc)        atomicAdd(&n_pos[b], posc);
    }
}

// ---------------- Pass C: CE per (b,p). float4 global loads -> LDS (contiguous),
// per-row scalar LDS reads, 4 lanes/row, 16 rows/wave, wave-private LDS region.
__global__ __launch_bounds__(256) void pass_c(const float* __restrict__ logits,
                                              const int* __restrict__ cls,
                                              float* __restrict__ ce_neg,
                                              float* __restrict__ acc) {
    __shared__ __align__(16) float sm[4 * 16 * 81 + 4];   // 4 waves x 1296 dwords (+pad)
    int tid = threadIdx.x;
    int lane = tid & 63;
    int wave = tid >> 6;
    int row0 = (blockIdx.x * 4 + wave) * 16;              // 16 rows per wave
    // stage: chunk = rows [row0, row0+16) = 1296 dwords = 324 float4 (16B-aligned)
    const float4* src = (const float4*)(logits + (size_t)row0 * CN);
    float4 t0 = src[lane];
    float4 t1 = src[lane + 64];
    float4 t2 = src[lane + 128];
    float4 t3 = src[lane + 192];
    float4 t4 = src[lane + 256];
    float4 t5 = (lane < 4) ? src[lane + 320] : make_float4(0.f, 0.f, 0.f, 0.f);
    float* wbase = sm + wave * 1296;
    float4* w4 = (float4*)wbase;
    w4[lane]       = t0;
    w4[lane + 64]  = t1;
    w4[lane + 128] = t2;
    w4[lane + 192] = t3;
    w4[lane + 256] = t4;
    if (lane < 4) w4[lane + 320] = t5;
    __syncthreads();
    int rr = lane >> 2, j = lane & 3;                     // 4 lanes per row
    const float* rbase = wbase + rr * CN;
    float v[21];
    #pragma unroll
    for (int u = 0; u < 21; u++) {
        int c = j + 4 * u;
        int cc = (c < CN) ? c : (CN - 1);
        float x = rbase[cc];
        v[u] = (c < CN) ? x : -INFINITY;
    }
    float m = v[0];
    #pragma unroll
    for (int u = 1; u < 21; u++) m = fmaxf(m, v[u]);
    m = fmaxf(m, __shfl_xor(m, 1));
    m = fmaxf(m, __shfl_xor(m, 2));
    float se = 0.0f;
    #pragma unroll
    for (int u = 0; u < 21; u++) se += __expf(v[u] - m);  // exp(-inf)=0
    se += __shfl_xor(se, 1);
    se += __shfl_xor(se, 2);
    float logZ = m + __logf(se);
    float cepos = 0.0f;
    if (j == 0) {
        int row = row0 + rr;
        int lab = cls[row];
        float xlab = rbase[lab];
        float ce = logZ - xlab;
        ce_neg[row] = (lab != 0) ? 0.0f : fmaxf(ce, 0.0f);  // clamp keeps bits monotonic
        cepos = (lab != 0) ? ce : 0.0f;
    }
    #pragma unroll
    for (int o = 1; o < 64; o <<= 1) cepos += __shfl_xor(cepos, o);
    if (lane == 0 && cepos != 0.0f) atomicAdd(&acc[1], cepos);
}

// ---------------- Pass D: per-image top-k(3*n_pos) sum of ce_neg, register-resident bisection
__global__ __launch_bounds__(256) void pass_d(const float* __restrict__ ce_neg,
                                              const int* __restrict__ n_pos,
                                              float* __restrict__ acc) {
    __shared__ int cnt[33];
    __shared__ float ssum;
    __shared__ int scnt;
    int b = blockIdx.x;
    int tid = threadIdx.x;
    int lane = tid & 63;
    float v[35];
    #pragma unroll
    for (int r = 0; r < 35; r++) {
        int i = r * 256 + tid;
        v[r] = (i < PN) ? ce_neg[(size_t)b * PN + i] : 0.0f;   // pad with 0 (neutral)
    }
    if (tid < 33) cnt[tid] = 0;
    if (tid == 0) { ssum = 0.0f; scnt = 0; }
    __syncthreads();
    int k = 3 * n_pos[b];
    if (k > PN) k = PN;
    if (k == 0) return;   // uniform across block
    unsigned lo = 0u, hi = 0x7f7fffffu;
    int iter = 0;
    if (k < PN) {
        while (lo < hi) {
            unsigned mid = lo + (hi - lo + 1u) / 2u;
            float mf = __uint_as_float(mid);
            int c = 0;
            #pragma unroll
            for (int r = 0; r < 35; r++) c += (v[r] >= mf) ? 1 : 0;
            #pragma unroll
            for (int o = 1; o < 64; o <<= 1) c += __shfl_xor(c, o);
            if (lane == 0) atomicAdd(&cnt[iter], c);
            __syncthreads();
            int tot = cnt[iter];
            if (tot >= k) lo = mid; else hi = mid - 1u;
            iter++;
        }
    }
    float vk = (k < PN) ? __uint_as_float(lo) : -1.0f;
    float s = 0.0f; int cg = 0;
    #pragma unroll
    for (int r = 0; r < 35; r++) {
        if (v[r] > vk) { s += v[r]; cg++; }
    }
    #pragma unroll
    for (int o = 1; o < 64; o <<= 1) { s += __shfl_xor(s, o); cg += __shfl_xor(cg, o); }
    if (lane == 0) { atomicAdd(&ssum, s); atomicAdd(&scnt, cg); }
    __syncthreads();
    if (tid == 0) {
        float res = (k < PN) ? (ssum + vk * (float)(k - scnt)) : ssum;
        atomicAdd(&acc[2], res);
    }
}

// ---------------- Pass E: finalize
__global__ void pass_e(const int* __restrict__ n_pos, const float* __restrict__ acc,
                       float* __restrict__ out) {
    if (threadIdx.x == 0) {
        int npt = 0;
        for (int b = 0; b < BN; b++) npt += n_pos[b];
        float n = (float)npt;
        out[0] = (acc[1] + acc[2]) / n + acc[0] / (n * 4.0f);
    }
}

extern "C" void kernel_launch(void* const* d_in, const int* in_sizes, int n_in,
                              void* d_out, int out_size, void* d_ws, size_t ws_size,
                              hipStream_t stream) {
    const float* pred_boxes  = (const float*)d_in[0];
    const float* pred_logits = (const float*)d_in[1];
    const float* boxes       = (const float*)d_in[2];
    const int*   labels      = (const int*)d_in[3];
    const float* prior       = (const float*)d_in[4];
    float* out = (float*)d_out;
    char* ws = (char*)d_ws;

    float* acc    = (float*)(ws + ACC_OFF);
    int*   n_pos  = (int*)(ws + NPOS_OFF);
    int*   idxg   = (int*)(ws + IDXG_OFF);
    int*   cls    = (int*)(ws + CLS_OFF);
    float* ce_neg = (float*)(ws + CEN_OFF);

    hipMemsetAsync(ws, 0, 512, stream);

    pass_a<<<BN * GN, 256, 0, stream>>>(boxes, prior, idxg);

    dim3 gb((PN + 255) / 256, BN);
    pass_b<<<gb, 256, 0, stream>>>(pred_boxes, boxes, labels, prior, idxg, cls, acc, n_pos);

    // 64*8732 rows / 16 rows-per-wave / 4 waves-per-block = 8732 blocks
    pass_c<<<(BN * PN) / 64, 256, 0, stream>>>(pred_logits, cls, ce_neg, acc);

    pass_d<<<BN, 256, 0, stream>>>(ce_neg, n_pos, acc);

    pass_e<<<1, 64, 0, stream>>>(n_pos, acc, out);
}

// Round 4
// 367.409 us; speedup vs baseline: 1.2091x; 1.0621x over previous
//
#include <hip/hip_runtime.h>
#include <math.h>

#define BN 64
#define PN 8732
#define CN 81
#define GN 32

// ws layout (bytes):
//   0  : float acc[3]  {sl1_sum, ce_pos_sum, hardneg_sum}
//   16 : int npt_total
//   20 : int done_counter
//   64 : int n_pos[BN]
//   512: int idx_per_gt[BN*GN]
//   8704: int cls[BN*PN]
//   2244096: float ce_neg[BN*PN]
#define ACC_OFF   0
#define NPT_OFF   16
#define DONE_OFF  20
#define NPOS_OFF  64
#define IDXG_OFF  512
#define CLS_OFF   8704
#define CEN_OFF   2244096

// ---------------- Pass A: idx_per_gt[b,g] = argmax_p IoU(gt, prior) (first occurrence)
__global__ __launch_bounds__(256) void pass_a(const float* __restrict__ boxes,
                                              const float* __restrict__ prior,
                                              int* __restrict__ idx_per_gt) {
    int b = blockIdx.x / GN, g = blockIdx.x % GN;
    const float4 gbv = *(const float4*)(boxes + (size_t)(b * GN + g) * 4);
    float gx0 = gbv.x, gy0 = gbv.y, gx1 = gbv.z, gy1 = gbv.w;
    float ga = (gx1 - gx0) * (gy1 - gy0);
    const float4* pr4 = (const float4*)prior;
    float best = -1.0f; int bi = PN;
    for (int p = threadIdx.x; p < PN; p += 256) {
        float4 pc = pr4[p];
        float cx = pc.x, cy = pc.y, w = pc.z, h = pc.w;
        float px0 = cx - w * 0.5f, py0 = cy - h * 0.5f;
        float px1 = cx + w * 0.5f, py1 = cy + h * 0.5f;
        float pa = (px1 - px0) * (py1 - py0);
        float ix = fminf(gx1, px1) - fmaxf(gx0, px0); ix = fmaxf(ix, 0.0f);
        float iy = fminf(gy1, py1) - fmaxf(gy0, py0); iy = fmaxf(iy, 0.0f);
        float inter = ix * iy;
        float iou = inter / (ga + pa - inter);
        if (iou > best) { best = iou; bi = p; }   // strict > keeps first occurrence
    }
    for (int o = 1; o < 64; o <<= 1) {
        float ov = __shfl_xor(best, o);
        int   oi = __shfl_xor(bi, o);
        if (ov > best || (ov == best && oi < bi)) { best = ov; bi = oi; }
    }
    __shared__ float sv[4]; __shared__ int si[4];
    int wid = threadIdx.x >> 6;
    if ((threadIdx.x & 63) == 0) { sv[wid] = best; si[wid] = bi; }
    __syncthreads();
    if (threadIdx.x == 0) {
        for (int w = 1; w < 4; w++)
            if (sv[w] > best || (sv[w] == best && si[w] < bi)) { best = sv[w]; bi = si[w]; }
        idx_per_gt[b * GN + g] = bi;
    }
}

// ---------------- Pass B: per-prior match, labels, smooth-L1 on positives
__global__ __launch_bounds__(256) void pass_b(const float* __restrict__ pred_boxes,
                                              const float* __restrict__ boxes,
                                              const int* __restrict__ labels,
                                              const float* __restrict__ prior,
                                              const int* __restrict__ idx_per_gt,
                                              int* __restrict__ cls,
                                              float* __restrict__ acc,
                                              int* __restrict__ n_pos,
                                              int* __restrict__ npt_total) {
    int b = blockIdx.y;
    __shared__ float bx[GN][4];
    __shared__ int lb[GN];
    __shared__ int ig[GN];
    int t = threadIdx.x;
    if (t < GN) {
        const float4 src = *(const float4*)(boxes + (size_t)(b * GN + t) * 4);
        bx[t][0] = src.x; bx[t][1] = src.y; bx[t][2] = src.z; bx[t][3] = src.w;
        lb[t] = labels[b * GN + t];
        ig[t] = idx_per_gt[b * GN + t];
    }
    __syncthreads();
    int p = blockIdx.x * 256 + t;
    float sl1 = 0.0f; int posc = 0;
    if (p < PN) {
        float4 pc = ((const float4*)prior)[p];
        float cx = pc.x, cy = pc.y, w = pc.z, h = pc.w;
        float px0 = cx - w * 0.5f, py0 = cy - h * 0.5f;
        float px1 = cx + w * 0.5f, py1 = cy + h * 0.5f;
        float pa = (px1 - px0) * (py1 - py0);
        float best = -1.0f; int bi = 0;
        for (int g = 0; g < GN; g++) {
            float gx0 = bx[g][0], gy0 = bx[g][1], gx1 = bx[g][2], gy1 = bx[g][3];
            float ga = (gx1 - gx0) * (gy1 - gy0);
            float ix = fminf(gx1, px1) - fmaxf(gx0, px0); ix = fmaxf(ix, 0.0f);
            float iy = fminf(gy1, py1) - fmaxf(gy0, py0); iy = fmaxf(iy, 0.0f);
            float inter = ix * iy;
            float iou = inter / (ga + pa - inter);
            if (iou > best) { best = iou; bi = g; }   // first occurrence along G
        }
        for (int g = 0; g < GN; g++) if (ig[g] == p) { bi = g; best = 1.0f; }  // last-g-wins
        int lab = (best < 0.5f) ? 0 : lb[bi];
        cls[(size_t)b * PN + p] = lab;
        if (lab != 0) {
            posc = 1;
            float gx0 = bx[bi][0], gy0 = bx[bi][1], gx1 = bx[bi][2], gy1 = bx[bi][3];
            float gcx = (gx0 + gx1) * 0.5f, gcy = (gy0 + gy1) * 0.5f;
            float gw = gx1 - gx0, gh = gy1 - gy0;
            float tb0 = (gcx - cx) / (w / 10.0f);
            float tb1 = (gcy - cy) / (h / 10.0f);
            float tb2 = __logf(gw / w) * 5.0f;
            float tb3 = __logf(gh / h) * 5.0f;
            float4 pb = *(const float4*)(pred_boxes + (size_t)(b * PN + p) * 4);
            float pbv[4] = {pb.x, pb.y, pb.z, pb.w};
            float tb[4] = {tb0, tb1, tb2, tb3};
            for (int i = 0; i < 4; i++) {
                float d = pbv[i] - tb[i];
                float ad = fabsf(d);
                sl1 += (ad < 1.0f) ? 0.5f * d * d : (ad - 0.5f);
            }
        }
    }
    for (int o = 1; o < 64; o <<= 1) {
        sl1  += __shfl_xor(sl1, o);
        posc += __shfl_xor(posc, o);
    }
    if ((t & 63) == 0) {
        if (sl1 != 0.0f) atomicAdd(&acc[0], sl1);
        if (posc) { atomicAdd(&n_pos[b], posc); atomicAdd(npt_total, posc); }
    }
}

// ---------------- Pass C: persistent, wave-private LDS, register double-buffered.
// chunk = 16 rows = 1296 dwords = 324 float4 (contiguous, 16B-aligned).
#define GRID_C 1792
#define NWAVES_C (GRID_C * 4)
#define NCHUNK ((BN * PN) / 16)     // 34928
__global__ __launch_bounds__(256) void pass_c(const float* __restrict__ logits,
                                              const int* __restrict__ cls,
                                              float* __restrict__ ce_neg,
                                              float* __restrict__ acc) {
    __shared__ __align__(16) float sm[4 * 1296];   // 20736 B -> 7 blocks/CU
    int tid = threadIdx.x, lane = tid & 63, wave = tid >> 6;
    float* wbase = sm + wave * 1296;
    float4* w4 = (float4*)wbase;
    int gw = blockIdx.x * 4 + wave;
    int rr = lane >> 2, j = lane & 3;              // 4 lanes per row
    const float* rbase = wbase + rr * CN;
    float cepos_acc = 0.0f;

    // prologue: stage chunk gw
    {
        const float4* src = (const float4*)logits + (size_t)gw * 324;
        float4 t0 = src[lane];
        float4 t1 = src[lane + 64];
        float4 t2 = src[lane + 128];
        float4 t3 = src[lane + 192];
        float4 t4 = src[lane + 256];
        float4 t5;
        if (lane < 4) t5 = src[lane + 320];
        w4[lane]       = t0;
        w4[lane + 64]  = t1;
        w4[lane + 128] = t2;
        w4[lane + 192] = t3;
        w4[lane + 256] = t4;
        if (lane < 4) w4[lane + 320] = t5;
    }

    for (int c = gw; c < NCHUNK; c += NWAVES_C) {
        int row = c * 16 + rr;
        // issue label load first (wait for it = vmcnt(6), prefetch stays in flight)
        int lab = (j == 0) ? cls[row] : 0;
        // issue prefetch of next chunk
        int cn = c + NWAVES_C;
        bool more = cn < NCHUNK;
        float4 n0, n1, n2, n3, n4, n5;
        if (more) {
            const float4* s2 = (const float4*)logits + (size_t)cn * 324;
            n0 = s2[lane];
            n1 = s2[lane + 64];
            n2 = s2[lane + 128];
            n3 = s2[lane + 192];
            n4 = s2[lane + 256];
            if (lane < 4) n5 = s2[lane + 320];
        }
        // read current chunk from LDS
        float v[21];
        #pragma unroll
        for (int u = 0; u < 21; u++) {
            int col = j + 4 * u;
            v[u] = (col < CN) ? rbase[(col < CN) ? col : 0] : -INFINITY;
        }
        float xlab = (j == 0) ? rbase[lab] : 0.0f;
        // compute
        float m = v[0];
        #pragma unroll
        for (int u = 1; u < 21; u++) m = fmaxf(m, v[u]);
        m = fmaxf(m, __shfl_xor(m, 1));
        m = fmaxf(m, __shfl_xor(m, 2));
        float se = 0.0f;
        #pragma unroll
        for (int u = 0; u < 21; u++) se += __expf(v[u] - m);   // exp(-inf)=0
        se += __shfl_xor(se, 1);
        se += __shfl_xor(se, 2);
        float logZ = m + __logf(se);
        if (j == 0) {
            float ce = logZ - xlab;
            ce_neg[row] = (lab != 0) ? 0.0f : fmaxf(ce, 0.0f);  // clamp keeps bits monotonic
            cepos_acc += (lab != 0) ? ce : 0.0f;
        }
        // stage next chunk (waits vmcnt on prefetch regs)
        if (more) {
            w4[lane]       = n0;
            w4[lane + 64]  = n1;
            w4[lane + 128] = n2;
            w4[lane + 192] = n3;
            w4[lane + 256] = n4;
            if (lane < 4) w4[lane + 320] = n5;
        }
    }
    #pragma unroll
    for (int o = 1; o < 64; o <<= 1) cepos_acc += __shfl_xor(cepos_acc, o);
    if (lane == 0 && cepos_acc != 0.0f) atomicAdd(&acc[1], cepos_acc);
}

// ---------------- Pass D: per-image top-k(3*n_pos) sum of ce_neg + fused finalize
__global__ __launch_bounds__(256) void pass_d(const float* __restrict__ ce_neg,
                                              const int* __restrict__ n_pos,
                                              float* __restrict__ acc,
                                              int* __restrict__ npt_total,
                                              int* __restrict__ done,
                                              float* __restrict__ out) {
    __shared__ int cnt[33];
    __shared__ float ssum;
    __shared__ int scnt;
    int b = blockIdx.x;
    int tid = threadIdx.x;
    int lane = tid & 63;
    const float4* cn4 = (const float4*)(ce_neg + (size_t)b * PN);
    float4 v[9];
    const float4 z4 = make_float4(0.f, 0.f, 0.f, 0.f);
    #pragma unroll
    for (int r = 0; r < 9; r++) {
        int i = r * 256 + tid;
        v[r] = (i < PN / 4) ? cn4[i] : z4;    // PN/4 = 2183 exact
    }
    if (tid < 33) cnt[tid] = 0;
    if (tid == 0) { ssum = 0.0f; scnt = 0; }
    __syncthreads();
    int k = 3 * n_pos[b];
    if (k > PN) k = PN;
    if (k > 0) {
        unsigned lo = 0u, hi = 0x7f7fffffu;
        int iter = 0;
        if (k < PN) {
            while (lo < hi) {
                unsigned mid = lo + (hi - lo + 1u) / 2u;
                float mf = __uint_as_float(mid);
                int c = 0;
                #pragma unroll
                for (int r = 0; r < 9; r++) {
                    c += (v[r].x >= mf) ? 1 : 0;
                    c += (v[r].y >= mf) ? 1 : 0;
                    c += (v[r].z >= mf) ? 1 : 0;
                    c += (v[r].w >= mf) ? 1 : 0;
                }
                #pragma unroll
                for (int o = 1; o < 64; o <<= 1) c += __shfl_xor(c, o);
                if (lane == 0) atomicAdd(&cnt[iter], c);
                __syncthreads();
                int tot = cnt[iter];
                if (tot >= k) lo = mid; else hi = mid - 1u;
                iter++;
            }
        }
        float vk = (k < PN) ? __uint_as_float(lo) : -1.0f;
        float s = 0.0f; int cg = 0;
        #pragma unroll
        for (int r = 0; r < 9; r++) {
            if (v[r].x > vk) { s += v[r].x; cg++; }
            if (v[r].y > vk) { s += v[r].y; cg++; }
            if (v[r].z > vk) { s += v[r].z; cg++; }
            if (v[r].w > vk) { s += v[r].w; cg++; }
        }
        #pragma unroll
        for (int o = 1; o < 64; o <<= 1) { s += __shfl_xor(s, o); cg += __shfl_xor(cg, o); }
        if (lane == 0) { atomicAdd(&ssum, s); atomicAdd(&scnt, cg); }
        __syncthreads();
        if (tid == 0) {
            float res = (k < PN) ? (ssum + vk * (float)(k - scnt)) : ssum;
            atomicAdd(&acc[2], res);
        }
    }
    // completion protocol: last block finalizes
    if (tid == 0) {
        __threadfence();
        int old = atomicAdd(done, 1);
        if (old == BN - 1) {
            __threadfence();
            float a0 = atomicAdd(&acc[0], 0.0f);
            float a1 = atomicAdd(&acc[1], 0.0f);
            float a2 = atomicAdd(&acc[2], 0.0f);
            int npt = atomicAdd(npt_total, 0);
            float n = (float)npt;
            out[0] = (a1 + a2) / n + a0 / (n * 4.0f);
        }
    }
}

extern "C" void kernel_launch(void* const* d_in, const int* in_sizes, int n_in,
                              void* d_out, int out_size, void* d_ws, size_t ws_size,
                              hipStream_t stream) {
    const float* pred_boxes  = (const float*)d_in[0];
    const float* pred_logits = (const float*)d_in[1];
    const float* boxes       = (const float*)d_in[2];
    const int*   labels      = (const int*)d_in[3];
    const float* prior       = (const float*)d_in[4];
    float* out = (float*)d_out;
    char* ws = (char*)d_ws;

    float* acc    = (float*)(ws + ACC_OFF);
    int*   npt    = (int*)(ws + NPT_OFF);
    int*   done   = (int*)(ws + DONE_OFF);
    int*   n_pos  = (int*)(ws + NPOS_OFF);
    int*   idxg   = (int*)(ws + IDXG_OFF);
    int*   cls    = (int*)(ws + CLS_OFF);
    float* ce_neg = (float*)(ws + CEN_OFF);

    hipMemsetAsync(ws, 0, 512, stream);

    pass_a<<<BN * GN, 256, 0, stream>>>(boxes, prior, idxg);

    dim3 gb((PN + 255) / 256, BN);
    pass_b<<<gb, 256, 0, stream>>>(pred_boxes, boxes, labels, prior, idxg, cls, acc, n_pos, npt);

    pass_c<<<GRID_C, 256, 0, stream>>>(pred_logits, cls, ce_neg, acc);

    pass_d<<<BN, 256, 0, stream>>>(ce_neg, n_pos, acc, npt, done, out);
}

// Round 5
// 121.400 us; speedup vs baseline: 3.6593x; 3.0264x over previous
//
#include <hip/hip_runtime.h>
#include <math.h>

#define BN 64
#define PN 8732
#define CN 81
#define GN 32

// ws layout (bytes):
//   0    : float acc2 (hardneg sum)        [concurrent atomic in pass_d]
//   4    : int done
//   64   : float acc0[64]  (sl1 partial sums, spread slots)
//   320  : int n_pos[64]
//   1024 : float acc1[256] (ce_pos partial sums, spread slots)
//   2048 : int idx_per_gt[BN*GN]
//   10240: int cls[BN*PN]
//   2245632: float ce_neg[BN*PN]
#define ACC2_OFF  0
#define DONE_OFF  4
#define ACC0_OFF  64
#define NPOS_OFF  320
#define ACC1_OFF  1024
#define IDXG_OFF  2048
#define CLS_OFF   10240
#define CEN_OFF   2245632

// ---------------- Pass A: idx_per_gt[b,g] = argmax_p IoU(gt, prior) (first occurrence)
__global__ __launch_bounds__(256) void pass_a(const float* __restrict__ boxes,
                                              const float* __restrict__ prior,
                                              int* __restrict__ idx_per_gt) {
    int b = blockIdx.x / GN, g = blockIdx.x % GN;
    const float4 gbv = *(const float4*)(boxes + (size_t)(b * GN + g) * 4);
    float gx0 = gbv.x, gy0 = gbv.y, gx1 = gbv.z, gy1 = gbv.w;
    float ga = (gx1 - gx0) * (gy1 - gy0);
    const float4* pr4 = (const float4*)prior;
    float best = -1.0f; int bi = PN;
    for (int p = threadIdx.x; p < PN; p += 256) {
        float4 pc = pr4[p];
        float cx = pc.x, cy = pc.y, w = pc.z, h = pc.w;
        float px0 = cx - w * 0.5f, py0 = cy - h * 0.5f;
        float px1 = cx + w * 0.5f, py1 = cy + h * 0.5f;
        float pa = (px1 - px0) * (py1 - py0);
        float ix = fminf(gx1, px1) - fmaxf(gx0, px0); ix = fmaxf(ix, 0.0f);
        float iy = fminf(gy1, py1) - fmaxf(gy0, py0); iy = fmaxf(iy, 0.0f);
        float inter = ix * iy;
        float iou = inter / (ga + pa - inter);
        if (iou > best) { best = iou; bi = p; }   // strict > keeps first occurrence
    }
    for (int o = 1; o < 64; o <<= 1) {
        float ov = __shfl_xor(best, o);
        int   oi = __shfl_xor(bi, o);
        if (ov > best || (ov == best && oi < bi)) { best = ov; bi = oi; }
    }
    __shared__ float sv[4]; __shared__ int si[4];
    int wid = threadIdx.x >> 6;
    if ((threadIdx.x & 63) == 0) { sv[wid] = best; si[wid] = bi; }
    __syncthreads();
    if (threadIdx.x == 0) {
        for (int w = 1; w < 4; w++)
            if (sv[w] > best || (sv[w] == best && si[w] < bi)) { best = sv[w]; bi = si[w]; }
        idx_per_gt[b * GN + g] = bi;
    }
}

// ---------------- Pass B: per-prior match, labels, smooth-L1 on positives.
// grid (4, BN): 4 blocks per image, 2183 priors each. Spread-slot atomics.
__global__ __launch_bounds__(256) void pass_b(const float* __restrict__ pred_boxes,
                                              const float* __restrict__ boxes,
                                              const int* __restrict__ labels,
                                              const float* __restrict__ prior,
                                              const int* __restrict__ idx_per_gt,
                                              int* __restrict__ cls,
                                              float* __restrict__ acc0,
                                              int* __restrict__ n_pos) {
    int b = blockIdx.y;
    __shared__ float bx[GN][4];
    __shared__ int lb[GN];
    __shared__ int ig[GN];
    int t = threadIdx.x;
    if (t < GN) {
        const float4 src = *(const float4*)(boxes + (size_t)(b * GN + t) * 4);
        bx[t][0] = src.x; bx[t][1] = src.y; bx[t][2] = src.z; bx[t][3] = src.w;
        lb[t] = labels[b * GN + t];
        ig[t] = idx_per_gt[b * GN + t];
    }
    __syncthreads();
    float sl1 = 0.0f; int posc = 0;
    int base = blockIdx.x * 2183;               // 4 * 2183 = 8732 exact
    for (int i = t; i < 2183; i += 256) {
        int p = base + i;
        float4 pc = ((const float4*)prior)[p];
        float cx = pc.x, cy = pc.y, w = pc.z, h = pc.w;
        float px0 = cx - w * 0.5f, py0 = cy - h * 0.5f;
        float px1 = cx + w * 0.5f, py1 = cy + h * 0.5f;
        float pa = (px1 - px0) * (py1 - py0);
        float best = -1.0f; int bi = 0;
        for (int g = 0; g < GN; g++) {
            float gx0 = bx[g][0], gy0 = bx[g][1], gx1 = bx[g][2], gy1 = bx[g][3];
            float ga = (gx1 - gx0) * (gy1 - gy0);
            float ix = fminf(gx1, px1) - fmaxf(gx0, px0); ix = fmaxf(ix, 0.0f);
            float iy = fminf(gy1, py1) - fmaxf(gy0, py0); iy = fmaxf(iy, 0.0f);
            float inter = ix * iy;
            float iou = inter / (ga + pa - inter);
            if (iou > best) { best = iou; bi = g; }   // first occurrence along G
        }
        for (int g = 0; g < GN; g++) if (ig[g] == p) { bi = g; best = 1.0f; }  // last-g-wins
        int lab = (best < 0.5f) ? 0 : lb[bi];
        cls[(size_t)b * PN + p] = lab;
        if (lab != 0) {
            posc++;
            float gx0 = bx[bi][0], gy0 = bx[bi][1], gx1 = bx[bi][2], gy1 = bx[bi][3];
            float gcx = (gx0 + gx1) * 0.5f, gcy = (gy0 + gy1) * 0.5f;
            float gw = gx1 - gx0, gh = gy1 - gy0;
            float tb0 = (gcx - cx) / (w / 10.0f);
            float tb1 = (gcy - cy) / (h / 10.0f);
            float tb2 = __logf(gw / w) * 5.0f;
            float tb3 = __logf(gh / h) * 5.0f;
            float4 pb = *(const float4*)(pred_boxes + (size_t)(b * PN + p) * 4);
            float pbv[4] = {pb.x, pb.y, pb.z, pb.w};
            float tb[4] = {tb0, tb1, tb2, tb3};
            for (int i2 = 0; i2 < 4; i2++) {
                float d = pbv[i2] - tb[i2];
                float ad = fabsf(d);
                sl1 += (ad < 1.0f) ? 0.5f * d * d : (ad - 0.5f);
            }
        }
    }
    for (int o = 1; o < 64; o <<= 1) {
        sl1  += __shfl_xor(sl1, o);
        posc += __shfl_xor(posc, o);
    }
    int wave = t >> 6;
    if ((t & 63) == 0) {
        if (sl1 != 0.0f) atomicAdd(&acc0[(b * 16 + blockIdx.x * 4 + wave) & 63], sl1);
        if (posc)        atomicAdd(&n_pos[b], posc);
    }
}

// ---------------- Pass C: persistent, wave-private LDS, register double-buffered.
// chunk = 16 rows = 1296 dwords = 324 float4 (contiguous, 16B-aligned).
#define GRID_C 1792
#define NWAVES_C (GRID_C * 4)
#define NCHUNK ((BN * PN) / 16)     // 34928
__global__ __launch_bounds__(256) void pass_c(const float* __restrict__ logits,
                                              const int* __restrict__ cls,
                                              float* __restrict__ ce_neg,
                                              float* __restrict__ acc1) {
    __shared__ __align__(16) float sm[4 * 1296];   // 20736 B -> 7 blocks/CU
    int tid = threadIdx.x, lane = tid & 63, wave = tid >> 6;
    float* wbase = sm + wave * 1296;
    float4* w4 = (float4*)wbase;
    int gw = blockIdx.x * 4 + wave;
    int rr = lane >> 2, j = lane & 3;              // 4 lanes per row
    const float* rbase = wbase + rr * CN;
    float cepos_acc = 0.0f;

    // prologue: stage chunk gw
    {
        const float4* src = (const float4*)logits + (size_t)gw * 324;
        float4 t0 = src[lane];
        float4 t1 = src[lane + 64];
        float4 t2 = src[lane + 128];
        float4 t3 = src[lane + 192];
        float4 t4 = src[lane + 256];
        float4 t5;
        if (lane < 4) t5 = src[lane + 320];
        w4[lane]       = t0;
        w4[lane + 64]  = t1;
        w4[lane + 128] = t2;
        w4[lane + 192] = t3;
        w4[lane + 256] = t4;
        if (lane < 4) w4[lane + 320] = t5;
    }

    for (int c = gw; c < NCHUNK; c += NWAVES_C) {
        int row = c * 16 + rr;
        int lab = (j == 0) ? cls[row] : 0;
        // prefetch next chunk (stays in flight across compute)
        int cn = c + NWAVES_C;
        bool more = cn < NCHUNK;
        float4 n0, n1, n2, n3, n4, n5;
        if (more) {
            const float4* s2 = (const float4*)logits + (size_t)cn * 324;
            n0 = s2[lane];
            n1 = s2[lane + 64];
            n2 = s2[lane + 128];
            n3 = s2[lane + 192];
            n4 = s2[lane + 256];
            if (lane < 4) n5 = s2[lane + 320];
        }
        // read current chunk from LDS
        float v[21];
        #pragma unroll
        for (int u = 0; u < 21; u++) {
            int col = j + 4 * u;
            v[u] = (col < CN) ? rbase[(col < CN) ? col : 0] : -INFINITY;
        }
        float xlab = (j == 0) ? rbase[lab] : 0.0f;
        float m = v[0];
        #pragma unroll
        for (int u = 1; u < 21; u++) m = fmaxf(m, v[u]);
        m = fmaxf(m, __shfl_xor(m, 1));
        m = fmaxf(m, __shfl_xor(m, 2));
        float se = 0.0f;
        #pragma unroll
        for (int u = 0; u < 21; u++) se += __expf(v[u] - m);   // exp(-inf)=0
        se += __shfl_xor(se, 1);
        se += __shfl_xor(se, 2);
        float logZ = m + __logf(se);
        if (j == 0) {
            float ce = logZ - xlab;
            ce_neg[row] = (lab != 0) ? 0.0f : fmaxf(ce, 0.0f);  // clamp keeps bits monotonic
            cepos_acc += (lab != 0) ? ce : 0.0f;
        }
        if (more) {
            w4[lane]       = n0;
            w4[lane + 64]  = n1;
            w4[lane + 128] = n2;
            w4[lane + 192] = n3;
            w4[lane + 256] = n4;
            if (lane < 4) w4[lane + 320] = n5;
        }
    }
    #pragma unroll
    for (int o = 1; o < 64; o <<= 1) cepos_acc += __shfl_xor(cepos_acc, o);
    if (lane == 0 && cepos_acc != 0.0f) atomicAdd(&acc1[gw & 255], cepos_acc);
}

// ---------------- Pass D: per-image top-k(3*n_pos) sum of ce_neg + fused finalize
__global__ __launch_bounds__(256) void pass_d(const float* __restrict__ ce_neg,
                                              const int* __restrict__ n_pos,
                                              const float* __restrict__ acc0,
                                              const float* __restrict__ acc1,
                                              float* __restrict__ acc2,
                                              int* __restrict__ done,
                                              float* __restrict__ out) {
    __shared__ int cnt[33];
    __shared__ float ssum;
    __shared__ int scnt;
    __shared__ int amlast;
    int b = blockIdx.x;
    int tid = threadIdx.x;
    int lane = tid & 63;
    const float4* cn4 = (const float4*)(ce_neg + (size_t)b * PN);
    float4 v[9];
    const float4 z4 = make_float4(0.f, 0.f, 0.f, 0.f);
    #pragma unroll
    for (int r = 0; r < 9; r++) {
        int i = r * 256 + tid;
        v[r] = (i < PN / 4) ? cn4[i] : z4;    // PN/4 = 2183 exact
    }
    if (tid < 33) cnt[tid] = 0;
    if (tid == 0) { ssum = 0.0f; scnt = 0; }
    __syncthreads();
    int k = 3 * n_pos[b];
    if (k > PN) k = PN;
    if (k > 0) {
        unsigned lo = 0u, hi = 0x7f7fffffu;
        int iter = 0;
        if (k < PN) {
            while (lo < hi) {
                unsigned mid = lo + (hi - lo + 1u) / 2u;
                float mf = __uint_as_float(mid);
                int c = 0;
                #pragma unroll
                for (int r = 0; r < 9; r++) {
                    c += (v[r].x >= mf) ? 1 : 0;
                    c += (v[r].y >= mf) ? 1 : 0;
                    c += (v[r].z >= mf) ? 1 : 0;
                    c += (v[r].w >= mf) ? 1 : 0;
                }
                #pragma unroll
                for (int o = 1; o < 64; o <<= 1) c += __shfl_xor(c, o);
                if (lane == 0) atomicAdd(&cnt[iter], c);
                __syncthreads();
                int tot = cnt[iter];
                if (tot >= k) lo = mid; else hi = mid - 1u;
                iter++;
            }
        }
        float vk = (k < PN) ? __uint_as_float(lo) : -1.0f;
        float s = 0.0f; int cg = 0;
        #pragma unroll
        for (int r = 0; r < 9; r++) {
            if (v[r].x > vk) { s += v[r].x; cg++; }
            if (v[r].y > vk) { s += v[r].y; cg++; }
            if (v[r].z > vk) { s += v[r].z; cg++; }
            if (v[r].w > vk) { s += v[r].w; cg++; }
        }
        #pragma unroll
        for (int o = 1; o < 64; o <<= 1) { s += __shfl_xor(s, o); cg += __shfl_xor(cg, o); }
        if (lane == 0) { atomicAdd(&ssum, s); atomicAdd(&scnt, cg); }
        __syncthreads();
        if (tid == 0) {
            float res = (k < PN) ? (ssum + vk * (float)(k - scnt)) : ssum;
            atomicAdd(acc2, res);
        }
    }
    // completion protocol: last block finalizes (wave-parallel slot reduction)
    if (tid == 0) {
        __threadfence();
        int old = atomicAdd(done, 1);
        amlast = (old == BN - 1) ? 1 : 0;
    }
    __syncthreads();
    if (amlast && tid < 64) {
        float sl1 = acc0[tid];
        int   np  = n_pos[tid];
        float cep = acc1[tid] + acc1[tid + 64] + acc1[tid + 128] + acc1[tid + 192];
        #pragma unroll
        for (int o = 1; o < 64; o <<= 1) {
            sl1 += __shfl_xor(sl1, o);
            cep += __shfl_xor(cep, o);
            np  += __shfl_xor(np, o);
        }
        if (tid == 0) {
            float a2 = atomicAdd(acc2, 0.0f);   // coherent read of concurrent sum
            float n = (float)np;
            out[0] = (cep + a2) / n + sl1 / (n * 4.0f);
        }
    }
}

extern "C" void kernel_launch(void* const* d_in, const int* in_sizes, int n_in,
                              void* d_out, int out_size, void* d_ws, size_t ws_size,
                              hipStream_t stream) {
    const float* pred_boxes  = (const float*)d_in[0];
    const float* pred_logits = (const float*)d_in[1];
    const float* boxes       = (const float*)d_in[2];
    const int*   labels      = (const int*)d_in[3];
    const float* prior       = (const float*)d_in[4];
    float* out = (float*)d_out;
    char* ws = (char*)d_ws;

    float* acc2   = (float*)(ws + ACC2_OFF);
    int*   done   = (int*)(ws + DONE_OFF);
    float* acc0   = (float*)(ws + ACC0_OFF);
    int*   n_pos  = (int*)(ws + NPOS_OFF);
    float* acc1   = (float*)(ws + ACC1_OFF);
    int*   idxg   = (int*)(ws + IDXG_OFF);
    int*   cls    = (int*)(ws + CLS_OFF);
    float* ce_neg = (float*)(ws + CEN_OFF);

    hipMemsetAsync(ws, 0, 2048, stream);

    pass_a<<<BN * GN, 256, 0, stream>>>(boxes, prior, idxg);

    dim3 gb(4, BN);
    pass_b<<<gb, 256, 0, stream>>>(pred_boxes, boxes, labels, prior, idxg, cls, acc0, n_pos);

    pass_c<<<GRID_C, 256, 0, stream>>>(pred_logits, cls, ce_neg, acc1);

    pass_d<<<BN, 256, 0, stream>>>(ce_neg, n_pos, acc0, acc1, acc2, done, out);
}

// Round 6
// 115.860 us; speedup vs baseline: 3.8343x; 1.0478x over previous
//
#include <hip/hip_runtime.h>
#include <math.h>

#define BN 64
#define PN 8732
#define CN 81
#define GN 32

// ws layout (bytes):
//   0    : float acc2 (hardneg sum)        [concurrent atomic in pass_d]
//   4    : int done
//   64   : float acc0[64]  (sl1 partial sums, spread slots)
//   320  : int n_pos[64]
//   1024 : float acc1[256] (ce_pos partial sums, spread slots)
//   2048 : int idx_per_gt[BN*GN]
//   10240: int cls[BN*PN]
//   2245632: float ce_neg[BN*PN]
#define ACC2_OFF  0
#define DONE_OFF  4
#define ACC0_OFF  64
#define NPOS_OFF  320
#define ACC1_OFF  1024
#define IDXG_OFF  2048
#define CLS_OFF   10240
#define CEN_OFF   2245632

// ---------------- Pass A: idx_per_gt[b,g] = argmax_p IoU(gt, prior) (first occurrence)
// Block 0 additionally zero-inits the first 2048 bytes of ws (accumulators),
// replacing a pathologically slow 2KB hipMemsetAsync fill (~102 us/replay).
__global__ __launch_bounds__(256) void pass_a(const float* __restrict__ boxes,
                                              const float* __restrict__ prior,
                                              int* __restrict__ idx_per_gt,
                                              int* __restrict__ wshead) {
    if (blockIdx.x == 0) {
        wshead[threadIdx.x] = 0;
        wshead[threadIdx.x + 256] = 0;
    }
    int b = blockIdx.x / GN, g = blockIdx.x % GN;
    const float4 gbv = *(const float4*)(boxes + (size_t)(b * GN + g) * 4);
    float gx0 = gbv.x, gy0 = gbv.y, gx1 = gbv.z, gy1 = gbv.w;
    float ga = (gx1 - gx0) * (gy1 - gy0);
    const float4* pr4 = (const float4*)prior;
    float best = -1.0f; int bi = PN;
    for (int p = threadIdx.x; p < PN; p += 256) {
        float4 pc = pr4[p];
        float cx = pc.x, cy = pc.y, w = pc.z, h = pc.w;
        float px0 = cx - w * 0.5f, py0 = cy - h * 0.5f;
        float px1 = cx + w * 0.5f, py1 = cy + h * 0.5f;
        float pa = (px1 - px0) * (py1 - py0);
        float ix = fminf(gx1, px1) - fmaxf(gx0, px0); ix = fmaxf(ix, 0.0f);
        float iy = fminf(gy1, py1) - fmaxf(gy0, py0); iy = fmaxf(iy, 0.0f);
        float inter = ix * iy;
        float iou = inter / (ga + pa - inter);
        if (iou > best) { best = iou; bi = p; }   // strict > keeps first occurrence
    }
    for (int o = 1; o < 64; o <<= 1) {
        float ov = __shfl_xor(best, o);
        int   oi = __shfl_xor(bi, o);
        if (ov > best || (ov == best && oi < bi)) { best = ov; bi = oi; }
    }
    __shared__ float sv[4]; __shared__ int si[4];
    int wid = threadIdx.x >> 6;
    if ((threadIdx.x & 63) == 0) { sv[wid] = best; si[wid] = bi; }
    __syncthreads();
    if (threadIdx.x == 0) {
        for (int w = 1; w < 4; w++)
            if (sv[w] > best || (sv[w] == best && si[w] < bi)) { best = sv[w]; bi = si[w]; }
        idx_per_gt[b * GN + g] = bi;
    }
}

// ---------------- Pass B: per-prior match, labels, smooth-L1 on positives.
// grid (4, BN): 4 blocks per image, 2183 priors each. Spread-slot atomics.
__global__ __launch_bounds__(256) void pass_b(const float* __restrict__ pred_boxes,
                                              const float* __restrict__ boxes,
                                              const int* __restrict__ labels,
                                              const float* __restrict__ prior,
                                              const int* __restrict__ idx_per_gt,
                                              int* __restrict__ cls,
                                              float* __restrict__ acc0,
                                              int* __restrict__ n_pos) {
    int b = blockIdx.y;
    __shared__ float bx[GN][4];
    __shared__ int lb[GN];
    __shared__ int ig[GN];
    int t = threadIdx.x;
    if (t < GN) {
        const float4 src = *(const float4*)(boxes + (size_t)(b * GN + t) * 4);
        bx[t][0] = src.x; bx[t][1] = src.y; bx[t][2] = src.z; bx[t][3] = src.w;
        lb[t] = labels[b * GN + t];
        ig[t] = idx_per_gt[b * GN + t];
    }
    __syncthreads();
    float sl1 = 0.0f; int posc = 0;
    int base = blockIdx.x * 2183;               // 4 * 2183 = 8732 exact
    for (int i = t; i < 2183; i += 256) {
        int p = base + i;
        float4 pc = ((const float4*)prior)[p];
        float cx = pc.x, cy = pc.y, w = pc.z, h = pc.w;
        float px0 = cx - w * 0.5f, py0 = cy - h * 0.5f;
        float px1 = cx + w * 0.5f, py1 = cy + h * 0.5f;
        float pa = (px1 - px0) * (py1 - py0);
        float best = -1.0f; int bi = 0;
        for (int g = 0; g < GN; g++) {
            float gx0 = bx[g][0], gy0 = bx[g][1], gx1 = bx[g][2], gy1 = bx[g][3];
            float ga = (gx1 - gx0) * (gy1 - gy0);
            float ix = fminf(gx1, px1) - fmaxf(gx0, px0); ix = fmaxf(ix, 0.0f);
            float iy = fminf(gy1, py1) - fmaxf(gy0, py0); iy = fmaxf(iy, 0.0f);
            float inter = ix * iy;
            float iou = inter / (ga + pa - inter);
            if (iou > best) { best = iou; bi = g; }   // first occurrence along G
        }
        for (int g = 0; g < GN; g++) if (ig[g] == p) { bi = g; best = 1.0f; }  // last-g-wins
        int lab = (best < 0.5f) ? 0 : lb[bi];
        cls[(size_t)b * PN + p] = lab;
        if (lab != 0) {
            posc++;
            float gx0 = bx[bi][0], gy0 = bx[bi][1], gx1 = bx[bi][2], gy1 = bx[bi][3];
            float gcx = (gx0 + gx1) * 0.5f, gcy = (gy0 + gy1) * 0.5f;
            float gw = gx1 - gx0, gh = gy1 - gy0;
            float tb0 = (gcx - cx) / (w / 10.0f);
            float tb1 = (gcy - cy) / (h / 10.0f);
            float tb2 = __logf(gw / w) * 5.0f;
            float tb3 = __logf(gh / h) * 5.0f;
            float4 pb = *(const float4*)(pred_boxes + (size_t)(b * PN + p) * 4);
            float pbv[4] = {pb.x, pb.y, pb.z, pb.w};
            float tb[4] = {tb0, tb1, tb2, tb3};
            for (int i2 = 0; i2 < 4; i2++) {
                float d = pbv[i2] - tb[i2];
                float ad = fabsf(d);
                sl1 += (ad < 1.0f) ? 0.5f * d * d : (ad - 0.5f);
            }
        }
    }
    for (int o = 1; o < 64; o <<= 1) {
        sl1  += __shfl_xor(sl1, o);
        posc += __shfl_xor(posc, o);
    }
    int wave = t >> 6;
    if ((t & 63) == 0) {
        if (sl1 != 0.0f) atomicAdd(&acc0[(b * 16 + blockIdx.x * 4 + wave) & 63], sl1);
        if (posc)        atomicAdd(&n_pos[b], posc);
    }
}

// ---------------- Pass C: persistent, wave-private LDS, register double-buffered.
// chunk = 16 rows = 1296 dwords = 324 float4 (contiguous, 16B-aligned).
#define GRID_C 1792
#define NWAVES_C (GRID_C * 4)
#define NCHUNK ((BN * PN) / 16)     // 34928
__global__ __launch_bounds__(256) void pass_c(const float* __restrict__ logits,
                                              const int* __restrict__ cls,
                                              float* __restrict__ ce_neg,
                                              float* __restrict__ acc1) {
    __shared__ __align__(16) float sm[4 * 1296];   // 20736 B -> 7 blocks/CU
    int tid = threadIdx.x, lane = tid & 63, wave = tid >> 6;
    float* wbase = sm + wave * 1296;
    float4* w4 = (float4*)wbase;
    int gw = blockIdx.x * 4 + wave;
    int rr = lane >> 2, j = lane & 3;              // 4 lanes per row
    const float* rbase = wbase + rr * CN;
    float cepos_acc = 0.0f;

    // prologue: stage chunk gw
    {
        const float4* src = (const float4*)logits + (size_t)gw * 324;
        float4 t0 = src[lane];
        float4 t1 = src[lane + 64];
        float4 t2 = src[lane + 128];
        float4 t3 = src[lane + 192];
        float4 t4 = src[lane + 256];
        float4 t5;
        if (lane < 4) t5 = src[lane + 320];
        w4[lane]       = t0;
        w4[lane + 64]  = t1;
        w4[lane + 128] = t2;
        w4[lane + 192] = t3;
        w4[lane + 256] = t4;
        if (lane < 4) w4[lane + 320] = t5;
    }

    for (int c = gw; c < NCHUNK; c += NWAVES_C) {
        int row = c * 16 + rr;
        int lab = (j == 0) ? cls[row] : 0;
        // prefetch next chunk (stays in flight across compute)
        int cn = c + NWAVES_C;
        bool more = cn < NCHUNK;
        float4 n0, n1, n2, n3, n4, n5;
        if (more) {
            const float4* s2 = (const float4*)logits + (size_t)cn * 324;
            n0 = s2[lane];
            n1 = s2[lane + 64];
            n2 = s2[lane + 128];
            n3 = s2[lane + 192];
            n4 = s2[lane + 256];
            if (lane < 4) n5 = s2[lane + 320];
        }
        // read current chunk from LDS
        float v[21];
        #pragma unroll
        for (int u = 0; u < 21; u++) {
            int col = j + 4 * u;
            v[u] = (col < CN) ? rbase[(col < CN) ? col : 0] : -INFINITY;
        }
        float xlab = (j == 0) ? rbase[lab] : 0.0f;
        float m = v[0];
        #pragma unroll
        for (int u = 1; u < 21; u++) m = fmaxf(m, v[u]);
        m = fmaxf(m, __shfl_xor(m, 1));
        m = fmaxf(m, __shfl_xor(m, 2));
        float se = 0.0f;
        #pragma unroll
        for (int u = 0; u < 21; u++) se += __expf(v[u] - m);   // exp(-inf)=0
        se += __shfl_xor(se, 1);
        se += __shfl_xor(se, 2);
        float logZ = m + __logf(se);
        if (j == 0) {
            float ce = logZ - xlab;
            ce_neg[row] = (lab != 0) ? 0.0f : fmaxf(ce, 0.0f);  // clamp keeps bits monotonic
            cepos_acc += (lab != 0) ? ce : 0.0f;
        }
        if (more) {
            w4[lane]       = n0;
            w4[lane + 64]  = n1;
            w4[lane + 128] = n2;
            w4[lane + 192] = n3;
            w4[lane + 256] = n4;
            if (lane < 4) w4[lane + 320] = n5;
        }
    }
    #pragma unroll
    for (int o = 1; o < 64; o <<= 1) cepos_acc += __shfl_xor(cepos_acc, o);
    if (lane == 0 && cepos_acc != 0.0f) atomicAdd(&acc1[gw & 255], cepos_acc);
}

// ---------------- Pass D: per-image top-k(3*n_pos) sum of ce_neg + fused finalize
__global__ __launch_bounds__(256) void pass_d(const float* __restrict__ ce_neg,
                                              const int* __restrict__ n_pos,
                                              const float* __restrict__ acc0,
                                              const float* __restrict__ acc1,
                                              float* __restrict__ acc2,
                                              int* __restrict__ done,
                                              float* __restrict__ out) {
    __shared__ int cnt[33];
    __shared__ float ssum;
    __shared__ int scnt;
    __shared__ int amlast;
    int b = blockIdx.x;
    int tid = threadIdx.x;
    int lane = tid & 63;
    const float4* cn4 = (const float4*)(ce_neg + (size_t)b * PN);
    float4 v[9];
    const float4 z4 = make_float4(0.f, 0.f, 0.f, 0.f);
    #pragma unroll
    for (int r = 0; r < 9; r++) {
        int i = r * 256 + tid;
        v[r] = (i < PN / 4) ? cn4[i] : z4;    // PN/4 = 2183 exact
    }
    if (tid < 33) cnt[tid] = 0;
    if (tid == 0) { ssum = 0.0f; scnt = 0; }
    __syncthreads();
    int k = 3 * n_pos[b];
    if (k > PN) k = PN;
    if (k > 0) {
        unsigned lo = 0u, hi = 0x7f7fffffu;
        int iter = 0;
        if (k < PN) {
            while (lo < hi) {
                unsigned mid = lo + (hi - lo + 1u) / 2u;
                float mf = __uint_as_float(mid);
                int c = 0;
                #pragma unroll
                for (int r = 0; r < 9; r++) {
                    c += (v[r].x >= mf) ? 1 : 0;
                    c += (v[r].y >= mf) ? 1 : 0;
                    c += (v[r].z >= mf) ? 1 : 0;
                    c += (v[r].w >= mf) ? 1 : 0;
                }
                #pragma unroll
                for (int o = 1; o < 64; o <<= 1) c += __shfl_xor(c, o);
                if (lane == 0) atomicAdd(&cnt[iter], c);
                __syncthreads();
                int tot = cnt[iter];
                if (tot >= k) lo = mid; else hi = mid - 1u;
                iter++;
            }
        }
        float vk = (k < PN) ? __uint_as_float(lo) : -1.0f;
        float s = 0.0f; int cg = 0;
        #pragma unroll
        for (int r = 0; r < 9; r++) {
            if (v[r].x > vk) { s += v[r].x; cg++; }
            if (v[r].y > vk) { s += v[r].y; cg++; }
            if (v[r].z > vk) { s += v[r].z; cg++; }
            if (v[r].w > vk) { s += v[r].w; cg++; }
        }
        #pragma unroll
        for (int o = 1; o < 64; o <<= 1) { s += __shfl_xor(s, o); cg += __shfl_xor(cg, o); }
        if (lane == 0) { atomicAdd(&ssum, s); atomicAdd(&scnt, cg); }
        __syncthreads();
        if (tid == 0) {
            float res = (k < PN) ? (ssum + vk * (float)(k - scnt)) : ssum;
            atomicAdd(acc2, res);
        }
    }
    // completion protocol: last block finalizes (wave-parallel slot reduction)
    if (tid == 0) {
        __threadfence();
        int old = atomicAdd(done, 1);
        amlast = (old == BN - 1) ? 1 : 0;
    }
    __syncthreads();
    if (amlast && tid < 64) {
        float sl1 = acc0[tid];
        int   np  = n_pos[tid];
        float cep = acc1[tid] + acc1[tid + 64] + acc1[tid + 128] + acc1[tid + 192];
        #pragma unroll
        for (int o = 1; o < 64; o <<= 1) {
            sl1 += __shfl_xor(sl1, o);
            cep += __shfl_xor(cep, o);
            np  += __shfl_xor(np, o);
        }
        if (tid == 0) {
            float a2 = atomicAdd(acc2, 0.0f);   // coherent read of concurrent sum
            float n = (float)np;
            out[0] = (cep + a2) / n + sl1 / (n * 4.0f);
        }
    }
}

extern "C" void kernel_launch(void* const* d_in, const int* in_sizes, int n_in,
                              void* d_out, int out_size, void* d_ws, size_t ws_size,
                              hipStream_t stream) {
    const float* pred_boxes  = (const float*)d_in[0];
    const float* pred_logits = (const float*)d_in[1];
    const float* boxes       = (const float*)d_in[2];
    const int*   labels      = (const int*)d_in[3];
    const float* prior       = (const float*)d_in[4];
    float* out = (float*)d_out;
    char* ws = (char*)d_ws;

    float* acc2   = (float*)(ws + ACC2_OFF);
    int*   done   = (int*)(ws + DONE_OFF);
    float* acc0   = (float*)(ws + ACC0_OFF);
    int*   n_pos  = (int*)(ws + NPOS_OFF);
    float* acc1   = (float*)(ws + ACC1_OFF);
    int*   idxg   = (int*)(ws + IDXG_OFF);
    int*   cls    = (int*)(ws + CLS_OFF);
    float* ce_neg = (float*)(ws + CEN_OFF);

    pass_a<<<BN * GN, 256, 0, stream>>>(boxes, prior, idxg, (int*)ws);

    dim3 gb(4, BN);
    pass_b<<<gb, 256, 0, stream>>>(pred_boxes, boxes, labels, prior, idxg, cls, acc0, n_pos);

    pass_c<<<GRID_C, 256, 0, stream>>>(pred_logits, cls, ce_neg, acc1);

    pass_d<<<BN, 256, 0, stream>>>(ce_neg, n_pos, acc0, acc1, acc2, done, out);
}